// Round 5
// baseline (664.423 us; speedup 1.0000x reference)
//
#include <hip/hip_runtime.h>
#include <math.h>

#define C 64
#define K 20
#define TPB 256            // 4 waves
#define ROWS_PER_TILE 128  // 4 waves x 32 rows
#define NT 8               // tiles per block -> 1024 points/block
#define ASTR 72            // Bs LDS row stride (bf16): b128 reads 2-way = free

// atomic buckets
#define NB 8
#define BSTR 512                 // floats per bucket
#define SCOFF (NB * BSTR)        // scale at ws[SCOFF..+63], shift at ws[SCOFF+64..+127]

typedef __attribute__((ext_vector_type(8))) short bf16x8;
typedef __attribute__((ext_vector_type(4))) float f32x4;

// ---------------- helpers ----------------

__device__ __forceinline__ float wave_reduce_add(float v) {
#pragma unroll
  for (int m = 32; m > 0; m >>= 1) v += __shfl_xor(v, m, 64);
  return v;
}

__device__ __forceinline__ unsigned short f2bf16(float x) {
  union { float f; unsigned u; } v; v.f = x;
  unsigned r = v.u + 0x7FFFu + ((v.u >> 16) & 1u);   // RTNE
  return (unsigned short)(r >> 16);
}

__device__ __forceinline__ bf16x8 cvt8(float4 lo, float4 hi) {
  bf16x8 r;
  r[0] = (short)f2bf16(lo.x); r[1] = (short)f2bf16(lo.y);
  r[2] = (short)f2bf16(lo.z); r[3] = (short)f2bf16(lo.w);
  r[4] = (short)f2bf16(hi.x); r[5] = (short)f2bf16(hi.y);
  r[6] = (short)f2bf16(hi.z); r[7] = (short)f2bf16(hi.w);
  return r;
}

// bucket layout (floats): [0]=sum w*nll [1]=sum w [2]=sum l1*m [3]=sum cos*m [4]=sum m
// [8..71]=sum_h  [72..135]=sum_h2 ; global: ws[SCOFF..]=BN scale, ws[SCOFF+64..]=BN shift

// ---------------- pass 1: pipelined MFMA dual-GEMM -> BN stats + CE (NO h spill) --------
// NT tiles per block; tile i+1 feat loads issued before tile i compute; zero barriers in
// the loop; CE fully in registers via 16-lane butterflies. b1 dropped (BN shift-invariant).
// Pure-read kernel: only output is ~130 atomicAdds per block at the end.

__global__ __launch_bounds__(TPB, 4)
void pass1_kernel(const float* __restrict__ feat,
                  const int* __restrict__ segment,
                  const float* __restrict__ W1,
                  const float* __restrict__ Wseg,
                  const float* __restrict__ bseg,
                  const float* __restrict__ cw,
                  float* __restrict__ ws, int n) {
  __shared__ __align__(16) unsigned short Bs[96 * ASTR];  // W1^T rows 0..63, Wseg^T 64..95
  __shared__ float cred[512];                             // [2][4 waves][64 ch]
  __shared__ float wpart[8];

  const int t = threadIdx.x;
  const int wv = t >> 6;          // 0..3
  const int L = t & 63;
  const int colL = L & 15;
  const int quad = L >> 4;
  const long long blockbase = (long long)blockIdx.x * (ROWS_PER_TILE * NT);
  const int rbase = wv * 32;

  float* bucket = ws + (blockIdx.x & (NB - 1)) * BSTR;

  // persistent per-lane accumulators (across tiles)
  float s1[4] = {0, 0, 0, 0}, s2[4] = {0, 0, 0, 0};
  float wnll = 0.f, wsum = 0.f;

  const float bsega = bseg[colL];
  const float bsegb = (colL < 4) ? bseg[16 + colL] : 0.f;

  float4 af[8];   // prefetched feat fragments [rt*4 + kh*2 + half]
  auto issue_tile = [&](int it) {
    const long long trow = blockbase + (long long)it * ROWS_PER_TILE + rbase;
    const float* frow = feat + (trow + colL) * C + quad * 8;
#pragma unroll
    for (int rt = 0; rt < 2; ++rt)
#pragma unroll
      for (int kh = 0; kh < 2; ++kh) {
        const float* p = frow + rt * (16 * C) + kh * 32;
        af[rt * 4 + kh * 2 + 0] = *(const float4*)p;
        af[rt * 4 + kh * 2 + 1] = *(const float4*)(p + 4);
      }
  };

  issue_tile(0);

  // stage W1^T (rows = out channel j, cols = k); covers tile-0 load latency
#pragma unroll
  for (int i = 0; i < 16; ++i) {
    int e = t + i * 256;                       // e = k*64 + j
    Bs[(e & 63) * ASTR + (e >> 6)] = f2bf16(W1[e]);
  }
  // stage Wseg^T padded to 32 output cols
#pragma unroll
  for (int i = 0; i < 8; ++i) {
    int e = t + i * 256;                       // over 64x32
    int k = e >> 5, j = e & 31;
    float v = (j < K) ? Wseg[k * K + j] : 0.0f;
    Bs[(64 + j) * ASTR + k] = f2bf16(v);
  }
  __syncthreads();   // Bs ready; never written again

  for (int it = 0; it < NT; ++it) {
    // segment rows for CURRENT tile (consumed in CE phase)
    int segc[8];
    {
      const long long trow = blockbase + (long long)it * ROWS_PER_TILE + rbase;
#pragma unroll
      for (int rt = 0; rt < 2; ++rt)
#pragma unroll
        for (int r = 0; r < 4; ++r)
          segc[rt * 4 + r] = segment[trow + rt * 16 + quad * 4 + r];
    }

    // consume prefetched feat (vmcnt wait folds here), then issue next tile
    bf16x8 a[2][2];
#pragma unroll
    for (int rt = 0; rt < 2; ++rt)
#pragma unroll
      for (int kh = 0; kh < 2; ++kh)
        a[rt][kh] = cvt8(af[rt * 4 + kh * 2], af[rt * 4 + kh * 2 + 1]);
    if (it + 1 < NT) issue_tile(it + 1);

    // ---- h columns (ct 0..3): 16 MFMAs ----
    f32x4 ah[2][4];
#pragma unroll
    for (int rt = 0; rt < 2; ++rt)
#pragma unroll
      for (int ct = 0; ct < 4; ++ct) ah[rt][ct] = (f32x4){0.f, 0.f, 0.f, 0.f};
#pragma unroll
    for (int kh = 0; kh < 2; ++kh) {
      const int k0 = kh * 32 + quad * 8;
#pragma unroll
      for (int ct = 0; ct < 4; ++ct) {
        bf16x8 b = *(const bf16x8*)(Bs + (ct * 16 + colL) * ASTR + k0);
        ah[0][ct] = __builtin_amdgcn_mfma_f32_16x16x32_bf16(a[0][kh], b, ah[0][ct], 0, 0, 0);
        ah[1][ct] = __builtin_amdgcn_mfma_f32_16x16x32_bf16(a[1][kh], b, ah[1][ct], 0, 0, 0);
      }
    }

    // ---- BN stats (registers only) ----
#pragma unroll
    for (int rt = 0; rt < 2; ++rt)
#pragma unroll
      for (int ct = 0; ct < 4; ++ct) {
        float v0 = ah[rt][ct][0], v1 = ah[rt][ct][1];
        float v2 = ah[rt][ct][2], v3 = ah[rt][ct][3];
        s1[ct] += v0 + v1 + v2 + v3;
        s2[ct] = __builtin_fmaf(v0, v0, s2[ct]);
        s2[ct] = __builtin_fmaf(v1, v1, s2[ct]);
        s2[ct] = __builtin_fmaf(v2, v2, s2[ct]);
        s2[ct] = __builtin_fmaf(v3, v3, s2[ct]);
      }

    // ---- logit columns (ct 4..5): 8 MFMAs ----
    f32x4 alg[2][2];
#pragma unroll
    for (int rt = 0; rt < 2; ++rt)
#pragma unroll
      for (int cc = 0; cc < 2; ++cc) alg[rt][cc] = (f32x4){0.f, 0.f, 0.f, 0.f};
#pragma unroll
    for (int kh = 0; kh < 2; ++kh) {
      const int k0 = kh * 32 + quad * 8;
#pragma unroll
      for (int cc = 0; cc < 2; ++cc) {
        bf16x8 b = *(const bf16x8*)(Bs + ((4 + cc) * 16 + colL) * ASTR + k0);
        alg[0][cc] = __builtin_amdgcn_mfma_f32_16x16x32_bf16(a[0][kh], b, alg[0][cc], 0, 0, 0);
        alg[1][cc] = __builtin_amdgcn_mfma_f32_16x16x32_bf16(a[1][kh], b, alg[1][cc], 0, 0, 0);
      }
    }

    // ---- CE fully in registers (16-lane butterflies, no LDS/barrier) ----
#pragma unroll
    for (int rt = 0; rt < 2; ++rt)
#pragma unroll
      for (int r = 0; r < 4; ++r) {
        float la = alg[rt][0][r] + bsega;                                   // col = colL
        float lb = (colL < 4) ? alg[rt][1][r] + bsegb : -3.0e38f;           // col = 16+colL
        const int sg = segc[rt * 4 + r];
        const bool valid = (sg != -1);
        const int tgt = valid ? sg : 0;
        float mx = fmaxf(la, lb);
        mx = fmaxf(mx, __shfl_xor(mx, 1, 64));
        mx = fmaxf(mx, __shfl_xor(mx, 2, 64));
        mx = fmaxf(mx, __shfl_xor(mx, 4, 64));
        mx = fmaxf(mx, __shfl_xor(mx, 8, 64));
        float e = __expf(la - mx) + ((colL < 4) ? __expf(lb - mx) : 0.f);
        float tp = ((colL == tgt) ? la : 0.f) + ((colL + 16 == tgt) ? lb : 0.f);
#pragma unroll
        for (int m = 1; m <= 8; m <<= 1) {
          e += __shfl_xor(e, m, 64);
          tp += __shfl_xor(tp, m, 64);
        }
        float nll = mx + __logf(e) - tp;
        float wct = cw[tgt];
        if (colL == 0) {
          float w = valid ? wct : 0.f;
          wnll += w * nll;
          wsum += w;
        }
      }
  }

  // ---- block-end reduction (amortized over NT tiles) ----
#pragma unroll
  for (int ct = 0; ct < 4; ++ct) {
    float a1 = s1[ct]; a1 += __shfl_xor(a1, 16, 64); a1 += __shfl_xor(a1, 32, 64);
    float a2 = s2[ct]; a2 += __shfl_xor(a2, 16, 64); a2 += __shfl_xor(a2, 32, 64);
    if (L < 16) { cred[wv * 64 + ct * 16 + colL] = a1; cred[256 + wv * 64 + ct * 16 + colL] = a2; }
  }
  {
    float rwn = wave_reduce_add(wnll);
    float rw = wave_reduce_add(wsum);
    if (L == 0) { wpart[wv * 2] = rwn; wpart[wv * 2 + 1] = rw; }
  }
  __syncthreads();
  if (t == 0) {
    atomicAdd(&bucket[0], wpart[0] + wpart[2] + wpart[4] + wpart[6]);
    atomicAdd(&bucket[1], wpart[1] + wpart[3] + wpart[5] + wpart[7]);
  }
  if (t < C) {
    float u1 = cred[t] + cred[64 + t] + cred[128 + t] + cred[192 + t];
    float u2 = cred[256 + t] + cred[320 + t] + cred[384 + t] + cred[448 + t];
    atomicAdd(&bucket[8 + t], u1);
    atomicAdd(&bucket[72 + t], u2);
  }
}

// ---------------- prep: fold BN stats into scale/shift once ----------------

__global__ void prep_kernel(const float* __restrict__ gamma,
                            const float* __restrict__ beta,
                            float* __restrict__ ws, int n) {
  int j = threadIdx.x;
  float s1 = 0.f, s2 = 0.f;
#pragma unroll
  for (int b = 0; b < NB; ++b) { s1 += ws[b * BSTR + 8 + j]; s2 += ws[b * BSTR + 72 + j]; }
  float inv_n = 1.0f / (float)n;
  float mean = s1 * inv_n;
  float var = fmaxf(s2 * inv_n - mean * mean, 0.0f);
  float sc = gamma[j] * rsqrtf(var + 1e-3f);
  ws[SCOFF + j] = sc;
  ws[SCOFF + 64 + j] = beta[j] - mean * sc;
}

// ---------------- pass 2: MFMA recompute of h (fp32 frags) + BN+ReLU+GEMV + losses -----
// Re-reads feat (268 MB) instead of an h round-trip (134 wr + 134 rd): identical ideal
// traffic, pure-read streaming, no write amplification. h never touches memory.

__global__ __launch_bounds__(TPB, 4)
void pass2_mfma(const float* __restrict__ feat,
                const float* __restrict__ coord,
                const int* __restrict__ instance,
                const float* __restrict__ centroid,
                const float* __restrict__ W1,
                const float* __restrict__ W2,
                const float* __restrict__ b2,
                float* __restrict__ ws, int n) {
  __shared__ __align__(16) unsigned short Bs[64 * ASTR];  // W1^T only
  __shared__ float part[4][3];

  const int t = threadIdx.x;
  const int wv = t >> 6, L = t & 63;
  const int colL = L & 15, quad = L >> 4;
  const long long blockbase = (long long)blockIdx.x * (ROWS_PER_TILE * NT);
  const int rbase = wv * 32;
  float* bucket = ws + (blockIdx.x & (NB - 1)) * BSTR;

  // per-lane BN scale/shift + W2 rows for channels ct*16+colL
  const float* ssc = ws + SCOFF;
  const float* ssh = ws + SCOFF + 64;
  float scv[4], shv[4], w20[4], w21[4], w22[4];
#pragma unroll
  for (int ct = 0; ct < 4; ++ct) {
    int j = ct * 16 + colL;
    scv[ct] = ssc[j];
    shv[ct] = ssh[j];
    w20[ct] = W2[j * 3 + 0];
    w21[ct] = W2[j * 3 + 1];
    w22[ct] = W2[j * 3 + 2];
  }
  const float bb0 = b2[0], bb1 = b2[1], bb2 = b2[2];

  float4 af[8];
  auto issue_tile = [&](int it) {
    const long long trow = blockbase + (long long)it * ROWS_PER_TILE + rbase;
    const float* frow = feat + (trow + colL) * C + quad * 8;
#pragma unroll
    for (int rt = 0; rt < 2; ++rt)
#pragma unroll
      for (int kh = 0; kh < 2; ++kh) {
        const float* p = frow + rt * (16 * C) + kh * 32;
        af[rt * 4 + kh * 2 + 0] = *(const float4*)p;
        af[rt * 4 + kh * 2 + 1] = *(const float4*)(p + 4);
      }
  };
  float pc[2][3], pg[2][3]; int pin[2];
  auto issue_pts = [&](int it) {
    if (colL < 4) {
      const long long rowb = blockbase + (long long)it * ROWS_PER_TILE +
                             rbase + quad * 4 + colL;
#pragma unroll
      for (int rt = 0; rt < 2; ++rt) {
        long long p = rowb + rt * 16;
        pc[rt][0] = coord[p * 3 + 0]; pc[rt][1] = coord[p * 3 + 1]; pc[rt][2] = coord[p * 3 + 2];
        pg[rt][0] = centroid[p * 3 + 0]; pg[rt][1] = centroid[p * 3 + 1]; pg[rt][2] = centroid[p * 3 + 2];
        pin[rt] = instance[p];
      }
    }
  };

  issue_tile(0);

  // stage W1^T; covers tile-0 load latency
#pragma unroll
  for (int i = 0; i < 16; ++i) {
    int e = t + i * 256;                       // e = k*64 + j
    Bs[(e & 63) * ASTR + (e >> 6)] = f2bf16(W1[e]);
  }
  __syncthreads();

  issue_pts(0);

  float l1a = 0.f, cosa = 0.f, ma = 0.f;

  for (int it = 0; it < NT; ++it) {
    bf16x8 a[2][2];
#pragma unroll
    for (int rt = 0; rt < 2; ++rt)
#pragma unroll
      for (int kh = 0; kh < 2; ++kh)
        a[rt][kh] = cvt8(af[rt * 4 + kh * 2], af[rt * 4 + kh * 2 + 1]);
    if (it + 1 < NT) issue_tile(it + 1);

    // h columns: 16 MFMAs (fp32 fragments, no bf16 rounding of h)
    f32x4 ah[2][4];
#pragma unroll
    for (int rt = 0; rt < 2; ++rt)
#pragma unroll
      for (int ct = 0; ct < 4; ++ct) ah[rt][ct] = (f32x4){0.f, 0.f, 0.f, 0.f};
#pragma unroll
    for (int kh = 0; kh < 2; ++kh) {
      const int k0 = kh * 32 + quad * 8;
#pragma unroll
      for (int ct = 0; ct < 4; ++ct) {
        bf16x8 b = *(const bf16x8*)(Bs + (ct * 16 + colL) * ASTR + k0);
        ah[0][ct] = __builtin_amdgcn_mfma_f32_16x16x32_bf16(a[0][kh], b, ah[0][ct], 0, 0, 0);
        ah[1][ct] = __builtin_amdgcn_mfma_f32_16x16x32_bf16(a[1][kh], b, ah[1][ct], 0, 0, 0);
      }
    }

    // BN+ReLU+W2 partials in-lane, butterfly over the 16-lane colL group
#pragma unroll
    for (int rt = 0; rt < 2; ++rt) {
      float d[12];
#pragma unroll
      for (int e = 0; e < 12; ++e) d[e] = 0.f;
#pragma unroll
      for (int ct = 0; ct < 4; ++ct) {
#pragma unroll
        for (int r = 0; r < 4; ++r) {
          float v = ah[rt][ct][r];
          float y = fmaxf(__builtin_fmaf(v, scv[ct], shv[ct]), 0.0f);
          d[r * 3 + 0] = __builtin_fmaf(y, w20[ct], d[r * 3 + 0]);
          d[r * 3 + 1] = __builtin_fmaf(y, w21[ct], d[r * 3 + 1]);
          d[r * 3 + 2] = __builtin_fmaf(y, w22[ct], d[r * 3 + 2]);
        }
      }
#pragma unroll
      for (int m = 1; m <= 8; m <<= 1)
#pragma unroll
        for (int e = 0; e < 12; ++e) d[e] += __shfl_xor(d[e], m, 64);
      if (colL < 4) {
        const int r = colL;
        float bp0 = d[r * 3 + 0] + bb0;
        float bp1 = d[r * 3 + 1] + bb1;
        float bp2 = d[r * 3 + 2] + bb2;
        float gx = pg[rt][0] - pc[rt][0];
        float gy = pg[rt][1] - pc[rt][1];
        float gz = pg[rt][2] - pc[rt][2];
        float m = (pin[rt] != -1) ? 1.0f : 0.0f;
        float l1 = fabsf(bp0 - gx) + fabsf(bp1 - gy) + fabsf(bp2 - gz);
        float npn = sqrtf(bp0 * bp0 + bp1 * bp1 + bp2 * bp2) + 1e-8f;
        float ngn = sqrtf(gx * gx + gy * gy + gz * gz) + 1e-8f;
        float cs = -(bp0 * gx + bp1 * gy + bp2 * gz) / (npn * ngn);
        l1a += l1 * m;
        cosa += cs * m;
        ma += m;
      }
    }
    if (it + 1 < NT) issue_pts(it + 1);
  }

  float r0 = wave_reduce_add(l1a);
  float r1 = wave_reduce_add(cosa);
  float r2 = wave_reduce_add(ma);
  if (L == 0) { part[wv][0] = r0; part[wv][1] = r1; part[wv][2] = r2; }
  __syncthreads();
  if (t == 0) {
    float a0 = 0, a1 = 0, a2 = 0;
#pragma unroll
    for (int k = 0; k < 4; ++k) { a0 += part[k][0]; a1 += part[k][1]; a2 += part[k][2]; }
    atomicAdd(&bucket[2], a0);
    atomicAdd(&bucket[3], a1);
    atomicAdd(&bucket[4], a2);
  }
}

// ---------------- finalize ----------------

__global__ void finalize_kernel(const float* __restrict__ ws, float* __restrict__ out) {
  if (threadIdx.x == 0 && blockIdx.x == 0) {
    float a0 = 0, a1 = 0, a2 = 0, a3 = 0, a4 = 0;
#pragma unroll
    for (int b = 0; b < NB; ++b) {
      const float* bk = ws + b * BSTR;
      a0 += bk[0]; a1 += bk[1]; a2 += bk[2]; a3 += bk[3]; a4 += bk[4];
    }
    float seg = a0 / a1;
    float den = a4 + 1e-8f;
    float l1 = a2 / den;
    float cs = a3 / den;
    out[0] = seg + l1 + cs;
    out[1] = seg;
    out[2] = l1;
    out[3] = cs;
  }
}

// ---------------- launch ----------------

extern "C" void kernel_launch(void* const* d_in, const int* in_sizes, int n_in,
                              void* d_out, int out_size, void* d_ws, size_t ws_size,
                              hipStream_t stream) {
  const float* feat = (const float*)d_in[0];
  const float* coord = (const float*)d_in[1];
  const int* segment = (const int*)d_in[2];
  const int* instance = (const int*)d_in[3];
  const float* centroid = (const float*)d_in[4];
  const float* W1 = (const float*)d_in[5];
  // d_in[6] = b1 : unused (BN train-mode output is invariant to channel shift)
  const float* gamma = (const float*)d_in[7];
  const float* beta = (const float*)d_in[8];
  const float* W2 = (const float*)d_in[9];
  const float* b2 = (const float*)d_in[10];
  const float* Wseg = (const float*)d_in[11];
  const float* bseg = (const float*)d_in[12];
  const float* cw = (const float*)d_in[13];

  const int n = in_sizes[0] / C;  // 1048576

  float* ws = (float*)d_ws;
  size_t zmax = (size_t)(NB * BSTR * 4);
  size_t zbytes = ws_size < zmax ? ws_size : zmax;
  hipMemsetAsync(d_ws, 0, zbytes, stream);

  const int nblk = n / (ROWS_PER_TILE * NT);   // 1024
  pass1_kernel<<<nblk, TPB, 0, stream>>>(feat, segment, W1, Wseg, bseg, cw, ws, n);
  prep_kernel<<<1, 64, 0, stream>>>(gamma, beta, ws, n);
  pass2_mfma<<<nblk, TPB, 0, stream>>>(feat, coord, instance, centroid,
                                       W1, W2, b2, ws, n);
  finalize_kernel<<<1, 1, 0, stream>>>(ws, (float*)d_out);
}

// Round 7
// 600.314 us; speedup vs baseline: 1.1068x; 1.1068x over previous
//
#include <hip/hip_runtime.h>
#include <math.h>

#define C 64
#define K 20
#define TPB 256            // 4 waves
#define ROWS_PER_TILE 128  // 4 waves x 32 rows
#define NT 8               // tiles per block -> 1024 points/block
#define ASTR 72            // Bs LDS row stride (bf16): b128 reads 2-way = free

// atomic buckets
#define NB 8
#define BSTR 512                 // floats per bucket
#define SCOFF (NB * BSTR)        // scale at ws[SCOFF..+63], shift at ws[SCOFF+64..+127]

typedef __attribute__((ext_vector_type(8))) short bf16x8;
typedef __attribute__((ext_vector_type(4))) float f32x4;

// ---------------- helpers ----------------

__device__ __forceinline__ float wave_reduce_add(float v) {
#pragma unroll
  for (int m = 32; m > 0; m >>= 1) v += __shfl_xor(v, m, 64);
  return v;
}

__device__ __forceinline__ unsigned short f2bf16(float x) {
  union { float f; unsigned u; } v; v.f = x;
  unsigned r = v.u + 0x7FFFu + ((v.u >> 16) & 1u);   // RTNE
  return (unsigned short)(r >> 16);
}

__device__ __forceinline__ bf16x8 cvt8(float4 lo, float4 hi) {
  bf16x8 r;
  r[0] = (short)f2bf16(lo.x); r[1] = (short)f2bf16(lo.y);
  r[2] = (short)f2bf16(lo.z); r[3] = (short)f2bf16(lo.w);
  r[4] = (short)f2bf16(hi.x); r[5] = (short)f2bf16(hi.y);
  r[6] = (short)f2bf16(hi.z); r[7] = (short)f2bf16(hi.w);
  return r;
}

// bucket layout (floats): [0]=sum w*nll [1]=sum w [2]=sum l1*m [3]=sum cos*m [4]=sum m
// [8..71]=sum_h  [72..135]=sum_h2 ; global: ws[SCOFF..]=BN scale, ws[SCOFF+64..]=BN shift

// ---------------- pass 1: pipelined MFMA dual-GEMM -> BN stats + CE (NO h spill) --------
// __launch_bounds__(256,3): 170-reg budget. (256,4)'s 128-reg cap forced the 32-reg `af`
// prefetch buffer into scratch (R4/R5: ~240 MB of phantom WRITE_SIZE + ~155 MB FETCH).
// NT tiles per block; tile i+1 feat loads issued before tile i compute; zero barriers in
// the loop; CE fully in registers via 16-lane butterflies. b1 dropped (BN shift-invariant).

__global__ __launch_bounds__(TPB, 3)
void pass1_kernel(const float* __restrict__ feat,
                  const int* __restrict__ segment,
                  const float* __restrict__ W1,
                  const float* __restrict__ Wseg,
                  const float* __restrict__ bseg,
                  const float* __restrict__ cw,
                  float* __restrict__ ws, int n) {
  __shared__ __align__(16) unsigned short Bs[96 * ASTR];  // W1^T rows 0..63, Wseg^T 64..95
  __shared__ float cred[512];                             // [2][4 waves][64 ch]
  __shared__ float wpart[8];

  const int t = threadIdx.x;
  const int wv = t >> 6;          // 0..3
  const int L = t & 63;
  const int colL = L & 15;
  const int quad = L >> 4;
  const long long blockbase = (long long)blockIdx.x * (ROWS_PER_TILE * NT);
  const int rbase = wv * 32;

  float* bucket = ws + (blockIdx.x & (NB - 1)) * BSTR;

  // persistent per-lane accumulators (across tiles)
  float s1[4] = {0, 0, 0, 0}, s2[4] = {0, 0, 0, 0};
  float wnll = 0.f, wsum = 0.f;

  const float bsega = bseg[colL];
  const float bsegb = (colL < 4) ? bseg[16 + colL] : 0.f;

  float4 af[8];   // prefetched feat fragments [rt*4 + kh*2 + half] -- must stay in VGPRs
  auto issue_tile = [&](int it) {
    const long long trow = blockbase + (long long)it * ROWS_PER_TILE + rbase;
    const float* frow = feat + (trow + colL) * C + quad * 8;
#pragma unroll
    for (int rt = 0; rt < 2; ++rt)
#pragma unroll
      for (int kh = 0; kh < 2; ++kh) {
        const float* p = frow + rt * (16 * C) + kh * 32;
        af[rt * 4 + kh * 2 + 0] = *(const float4*)p;
        af[rt * 4 + kh * 2 + 1] = *(const float4*)(p + 4);
      }
  };

  issue_tile(0);

  // stage W1^T (rows = out channel j, cols = k); covers tile-0 load latency
#pragma unroll
  for (int i = 0; i < 16; ++i) {
    int e = t + i * 256;                       // e = k*64 + j
    Bs[(e & 63) * ASTR + (e >> 6)] = f2bf16(W1[e]);
  }
  // stage Wseg^T padded to 32 output cols
#pragma unroll
  for (int i = 0; i < 8; ++i) {
    int e = t + i * 256;                       // over 64x32
    int k = e >> 5, j = e & 31;
    float v = (j < K) ? Wseg[k * K + j] : 0.0f;
    Bs[(64 + j) * ASTR + k] = f2bf16(v);
  }
  __syncthreads();   // Bs ready; never written again

  for (int it = 0; it < NT; ++it) {
    // segment rows for CURRENT tile (consumed in CE phase)
    int segc[8];
    {
      const long long trow = blockbase + (long long)it * ROWS_PER_TILE + rbase;
#pragma unroll
      for (int rt = 0; rt < 2; ++rt)
#pragma unroll
        for (int r = 0; r < 4; ++r)
          segc[rt * 4 + r] = segment[trow + rt * 16 + quad * 4 + r];
    }

    // consume prefetched feat (vmcnt wait folds here), then issue next tile
    bf16x8 a[2][2];
#pragma unroll
    for (int rt = 0; rt < 2; ++rt)
#pragma unroll
      for (int kh = 0; kh < 2; ++kh)
        a[rt][kh] = cvt8(af[rt * 4 + kh * 2], af[rt * 4 + kh * 2 + 1]);
    if (it + 1 < NT) issue_tile(it + 1);

    // ---- h columns (ct 0..3): 16 MFMAs ----
    f32x4 ah[2][4];
#pragma unroll
    for (int rt = 0; rt < 2; ++rt)
#pragma unroll
      for (int ct = 0; ct < 4; ++ct) ah[rt][ct] = (f32x4){0.f, 0.f, 0.f, 0.f};
#pragma unroll
    for (int kh = 0; kh < 2; ++kh) {
      const int k0 = kh * 32 + quad * 8;
#pragma unroll
      for (int ct = 0; ct < 4; ++ct) {
        bf16x8 b = *(const bf16x8*)(Bs + (ct * 16 + colL) * ASTR + k0);
        ah[0][ct] = __builtin_amdgcn_mfma_f32_16x16x32_bf16(a[0][kh], b, ah[0][ct], 0, 0, 0);
        ah[1][ct] = __builtin_amdgcn_mfma_f32_16x16x32_bf16(a[1][kh], b, ah[1][ct], 0, 0, 0);
      }
    }

    // ---- BN stats (registers only) ----
#pragma unroll
    for (int rt = 0; rt < 2; ++rt)
#pragma unroll
      for (int ct = 0; ct < 4; ++ct) {
        float v0 = ah[rt][ct][0], v1 = ah[rt][ct][1];
        float v2 = ah[rt][ct][2], v3 = ah[rt][ct][3];
        s1[ct] += v0 + v1 + v2 + v3;
        s2[ct] = __builtin_fmaf(v0, v0, s2[ct]);
        s2[ct] = __builtin_fmaf(v1, v1, s2[ct]);
        s2[ct] = __builtin_fmaf(v2, v2, s2[ct]);
        s2[ct] = __builtin_fmaf(v3, v3, s2[ct]);
      }

    // ---- logit columns (ct 4..5): 8 MFMAs ----
    f32x4 alg[2][2];
#pragma unroll
    for (int rt = 0; rt < 2; ++rt)
#pragma unroll
      for (int cc = 0; cc < 2; ++cc) alg[rt][cc] = (f32x4){0.f, 0.f, 0.f, 0.f};
#pragma unroll
    for (int kh = 0; kh < 2; ++kh) {
      const int k0 = kh * 32 + quad * 8;
#pragma unroll
      for (int cc = 0; cc < 2; ++cc) {
        bf16x8 b = *(const bf16x8*)(Bs + ((4 + cc) * 16 + colL) * ASTR + k0);
        alg[0][cc] = __builtin_amdgcn_mfma_f32_16x16x32_bf16(a[0][kh], b, alg[0][cc], 0, 0, 0);
        alg[1][cc] = __builtin_amdgcn_mfma_f32_16x16x32_bf16(a[1][kh], b, alg[1][cc], 0, 0, 0);
      }
    }

    // ---- CE fully in registers (16-lane butterflies, no LDS/barrier) ----
#pragma unroll
    for (int rt = 0; rt < 2; ++rt)
#pragma unroll
      for (int r = 0; r < 4; ++r) {
        float la = alg[rt][0][r] + bsega;                                   // col = colL
        float lb = (colL < 4) ? alg[rt][1][r] + bsegb : -3.0e38f;           // col = 16+colL
        const int sg = segc[rt * 4 + r];
        const bool valid = (sg != -1);
        const int tgt = valid ? sg : 0;
        float mx = fmaxf(la, lb);
        mx = fmaxf(mx, __shfl_xor(mx, 1, 64));
        mx = fmaxf(mx, __shfl_xor(mx, 2, 64));
        mx = fmaxf(mx, __shfl_xor(mx, 4, 64));
        mx = fmaxf(mx, __shfl_xor(mx, 8, 64));
        float e = __expf(la - mx) + ((colL < 4) ? __expf(lb - mx) : 0.f);
        float tp = ((colL == tgt) ? la : 0.f) + ((colL + 16 == tgt) ? lb : 0.f);
#pragma unroll
        for (int m = 1; m <= 8; m <<= 1) {
          e += __shfl_xor(e, m, 64);
          tp += __shfl_xor(tp, m, 64);
        }
        float nll = mx + __logf(e) - tp;
        float wct = cw[tgt];
        if (colL == 0) {
          float w = valid ? wct : 0.f;
          wnll += w * nll;
          wsum += w;
        }
      }
  }

  // ---- block-end reduction (amortized over NT tiles) ----
#pragma unroll
  for (int ct = 0; ct < 4; ++ct) {
    float a1 = s1[ct]; a1 += __shfl_xor(a1, 16, 64); a1 += __shfl_xor(a1, 32, 64);
    float a2 = s2[ct]; a2 += __shfl_xor(a2, 16, 64); a2 += __shfl_xor(a2, 32, 64);
    if (L < 16) { cred[wv * 64 + ct * 16 + colL] = a1; cred[256 + wv * 64 + ct * 16 + colL] = a2; }
  }
  {
    float rwn = wave_reduce_add(wnll);
    float rw = wave_reduce_add(wsum);
    if (L == 0) { wpart[wv * 2] = rwn; wpart[wv * 2 + 1] = rw; }
  }
  __syncthreads();
  if (t == 0) {
    atomicAdd(&bucket[0], wpart[0] + wpart[2] + wpart[4] + wpart[6]);
    atomicAdd(&bucket[1], wpart[1] + wpart[3] + wpart[5] + wpart[7]);
  }
  if (t < C) {
    float u1 = cred[t] + cred[64 + t] + cred[128 + t] + cred[192 + t];
    float u2 = cred[256 + t] + cred[320 + t] + cred[384 + t] + cred[448 + t];
    atomicAdd(&bucket[8 + t], u1);
    atomicAdd(&bucket[72 + t], u2);
  }
}

// ---------------- prep: fold BN stats into scale/shift once ----------------

__global__ void prep_kernel(const float* __restrict__ gamma,
                            const float* __restrict__ beta,
                            float* __restrict__ ws, int n) {
  int j = threadIdx.x;
  float s1 = 0.f, s2 = 0.f;
#pragma unroll
  for (int b = 0; b < NB; ++b) { s1 += ws[b * BSTR + 8 + j]; s2 += ws[b * BSTR + 72 + j]; }
  float inv_n = 1.0f / (float)n;
  float mean = s1 * inv_n;
  float var = fmaxf(s2 * inv_n - mean * mean, 0.0f);
  float sc = gamma[j] * rsqrtf(var + 1e-3f);
  ws[SCOFF + j] = sc;
  ws[SCOFF + 64 + j] = beta[j] - mean * sc;
}

// ---------------- pass 2: MFMA recompute of h (fp32 frags) + BN+ReLU+GEMV + losses -----
// Re-reads feat instead of an h round-trip: identical ideal traffic, pure-read streaming.
// Same (256,3) budget fix as pass1.

__global__ __launch_bounds__(TPB, 3)
void pass2_mfma(const float* __restrict__ feat,
                const float* __restrict__ coord,
                const int* __restrict__ instance,
                const float* __restrict__ centroid,
                const float* __restrict__ W1,
                const float* __restrict__ W2,
                const float* __restrict__ b2,
                float* __restrict__ ws, int n) {
  __shared__ __align__(16) unsigned short Bs[64 * ASTR];  // W1^T only
  __shared__ float part[4][3];

  const int t = threadIdx.x;
  const int wv = t >> 6, L = t & 63;
  const int colL = L & 15, quad = L >> 4;
  const long long blockbase = (long long)blockIdx.x * (ROWS_PER_TILE * NT);
  const int rbase = wv * 32;
  float* bucket = ws + (blockIdx.x & (NB - 1)) * BSTR;

  // per-lane BN scale/shift + W2 rows for channels ct*16+colL
  const float* ssc = ws + SCOFF;
  const float* ssh = ws + SCOFF + 64;
  float scv[4], shv[4], w20[4], w21[4], w22[4];
#pragma unroll
  for (int ct = 0; ct < 4; ++ct) {
    int j = ct * 16 + colL;
    scv[ct] = ssc[j];
    shv[ct] = ssh[j];
    w20[ct] = W2[j * 3 + 0];
    w21[ct] = W2[j * 3 + 1];
    w22[ct] = W2[j * 3 + 2];
  }
  const float bb0 = b2[0], bb1 = b2[1], bb2 = b2[2];

  float4 af[8];
  auto issue_tile = [&](int it) {
    const long long trow = blockbase + (long long)it * ROWS_PER_TILE + rbase;
    const float* frow = feat + (trow + colL) * C + quad * 8;
#pragma unroll
    for (int rt = 0; rt < 2; ++rt)
#pragma unroll
      for (int kh = 0; kh < 2; ++kh) {
        const float* p = frow + rt * (16 * C) + kh * 32;
        af[rt * 4 + kh * 2 + 0] = *(const float4*)p;
        af[rt * 4 + kh * 2 + 1] = *(const float4*)(p + 4);
      }
  };
  float pc[2][3], pg[2][3]; int pin[2];
  auto issue_pts = [&](int it) {
    if (colL < 4) {
      const long long rowb = blockbase + (long long)it * ROWS_PER_TILE +
                             rbase + quad * 4 + colL;
#pragma unroll
      for (int rt = 0; rt < 2; ++rt) {
        long long p = rowb + rt * 16;
        pc[rt][0] = coord[p * 3 + 0]; pc[rt][1] = coord[p * 3 + 1]; pc[rt][2] = coord[p * 3 + 2];
        pg[rt][0] = centroid[p * 3 + 0]; pg[rt][1] = centroid[p * 3 + 1]; pg[rt][2] = centroid[p * 3 + 2];
        pin[rt] = instance[p];
      }
    }
  };

  issue_tile(0);

  // stage W1^T; covers tile-0 load latency
#pragma unroll
  for (int i = 0; i < 16; ++i) {
    int e = t + i * 256;                       // e = k*64 + j
    Bs[(e & 63) * ASTR + (e >> 6)] = f2bf16(W1[e]);
  }
  __syncthreads();

  issue_pts(0);

  float l1a = 0.f, cosa = 0.f, ma = 0.f;

  for (int it = 0; it < NT; ++it) {
    bf16x8 a[2][2];
#pragma unroll
    for (int rt = 0; rt < 2; ++rt)
#pragma unroll
      for (int kh = 0; kh < 2; ++kh)
        a[rt][kh] = cvt8(af[rt * 4 + kh * 2], af[rt * 4 + kh * 2 + 1]);
    if (it + 1 < NT) issue_tile(it + 1);

    // h columns: 16 MFMAs (fp32 fragments, no bf16 rounding of h)
    f32x4 ah[2][4];
#pragma unroll
    for (int rt = 0; rt < 2; ++rt)
#pragma unroll
      for (int ct = 0; ct < 4; ++ct) ah[rt][ct] = (f32x4){0.f, 0.f, 0.f, 0.f};
#pragma unroll
    for (int kh = 0; kh < 2; ++kh) {
      const int k0 = kh * 32 + quad * 8;
#pragma unroll
      for (int ct = 0; ct < 4; ++ct) {
        bf16x8 b = *(const bf16x8*)(Bs + (ct * 16 + colL) * ASTR + k0);
        ah[0][ct] = __builtin_amdgcn_mfma_f32_16x16x32_bf16(a[0][kh], b, ah[0][ct], 0, 0, 0);
        ah[1][ct] = __builtin_amdgcn_mfma_f32_16x16x32_bf16(a[1][kh], b, ah[1][ct], 0, 0, 0);
      }
    }

    // BN+ReLU+W2 partials in-lane, butterfly over the 16-lane colL group
#pragma unroll
    for (int rt = 0; rt < 2; ++rt) {
      float d[12];
#pragma unroll
      for (int e = 0; e < 12; ++e) d[e] = 0.f;
#pragma unroll
      for (int ct = 0; ct < 4; ++ct) {
#pragma unroll
        for (int r = 0; r < 4; ++r) {
          float v = ah[rt][ct][r];
          float y = fmaxf(__builtin_fmaf(v, scv[ct], shv[ct]), 0.0f);
          d[r * 3 + 0] = __builtin_fmaf(y, w20[ct], d[r * 3 + 0]);
          d[r * 3 + 1] = __builtin_fmaf(y, w21[ct], d[r * 3 + 1]);
          d[r * 3 + 2] = __builtin_fmaf(y, w22[ct], d[r * 3 + 2]);
        }
      }
#pragma unroll
      for (int m = 1; m <= 8; m <<= 1)
#pragma unroll
        for (int e = 0; e < 12; ++e) d[e] += __shfl_xor(d[e], m, 64);
      if (colL < 4) {
        const int r = colL;
        float bp0 = d[r * 3 + 0] + bb0;
        float bp1 = d[r * 3 + 1] + bb1;
        float bp2 = d[r * 3 + 2] + bb2;
        float gx = pg[rt][0] - pc[rt][0];
        float gy = pg[rt][1] - pc[rt][1];
        float gz = pg[rt][2] - pc[rt][2];
        float m = (pin[rt] != -1) ? 1.0f : 0.0f;
        float l1 = fabsf(bp0 - gx) + fabsf(bp1 - gy) + fabsf(bp2 - gz);
        float npn = sqrtf(bp0 * bp0 + bp1 * bp1 + bp2 * bp2) + 1e-8f;
        float ngn = sqrtf(gx * gx + gy * gy + gz * gz) + 1e-8f;
        float cs = -(bp0 * gx + bp1 * gy + bp2 * gz) / (npn * ngn);
        l1a += l1 * m;
        cosa += cs * m;
        ma += m;
      }
    }
    if (it + 1 < NT) issue_pts(it + 1);
  }

  float r0 = wave_reduce_add(l1a);
  float r1 = wave_reduce_add(cosa);
  float r2 = wave_reduce_add(ma);
  if (L == 0) { part[wv][0] = r0; part[wv][1] = r1; part[wv][2] = r2; }
  __syncthreads();
  if (t == 0) {
    float a0 = 0, a1 = 0, a2 = 0;
#pragma unroll
    for (int k = 0; k < 4; ++k) { a0 += part[k][0]; a1 += part[k][1]; a2 += part[k][2]; }
    atomicAdd(&bucket[2], a0);
    atomicAdd(&bucket[3], a1);
    atomicAdd(&bucket[4], a2);
  }
}

// ---------------- finalize ----------------

__global__ void finalize_kernel(const float* __restrict__ ws, float* __restrict__ out) {
  if (threadIdx.x == 0 && blockIdx.x == 0) {
    float a0 = 0, a1 = 0, a2 = 0, a3 = 0, a4 = 0;
#pragma unroll
    for (int b = 0; b < NB; ++b) {
      const float* bk = ws + b * BSTR;
      a0 += bk[0]; a1 += bk[1]; a2 += bk[2]; a3 += bk[3]; a4 += bk[4];
    }
    float seg = a0 / a1;
    float den = a4 + 1e-8f;
    float l1 = a2 / den;
    float cs = a3 / den;
    out[0] = seg + l1 + cs;
    out[1] = seg;
    out[2] = l1;
    out[3] = cs;
  }
}

// ---------------- launch ----------------

extern "C" void kernel_launch(void* const* d_in, const int* in_sizes, int n_in,
                              void* d_out, int out_size, void* d_ws, size_t ws_size,
                              hipStream_t stream) {
  const float* feat = (const float*)d_in[0];
  const float* coord = (const float*)d_in[1];
  const int* segment = (const int*)d_in[2];
  const int* instance = (const int*)d_in[3];
  const float* centroid = (const float*)d_in[4];
  const float* W1 = (const float*)d_in[5];
  // d_in[6] = b1 : unused (BN train-mode output is invariant to channel shift)
  const float* gamma = (const float*)d_in[7];
  const float* beta = (const float*)d_in[8];
  const float* W2 = (const float*)d_in[9];
  const float* b2 = (const float*)d_in[10];
  const float* Wseg = (const float*)d_in[11];
  const float* bseg = (const float*)d_in[12];
  const float* cw = (const float*)d_in[13];

  const int n = in_sizes[0] / C;  // 1048576

  float* ws = (float*)d_ws;
  size_t zmax = (size_t)(NB * BSTR * 4);
  size_t zbytes = ws_size < zmax ? ws_size : zmax;
  hipMemsetAsync(d_ws, 0, zbytes, stream);

  const int nblk = n / (ROWS_PER_TILE * NT);   // 1024
  pass1_kernel<<<nblk, TPB, 0, stream>>>(feat, segment, W1, Wseg, bseg, cw, ws, n);
  prep_kernel<<<1, 64, 0, stream>>>(gamma, beta, ws, n);
  pass2_mfma<<<nblk, TPB, 0, stream>>>(feat, coord, instance, centroid,
                                       W1, W2, b2, ws, n);
  finalize_kernel<<<1, 1, 0, stream>>>(ws, (float*)d_out);
}

// Round 8
// 532.908 us; speedup vs baseline: 1.2468x; 1.1265x over previous
//
#include <hip/hip_runtime.h>
#include <math.h>

#define C 64
#define K 20
#define TPB 256            // 4 waves
#define ROWS_PER_TILE 128  // 4 waves x 32 rows
#define NT 4               // tiles per block -> 512 points/block, grid 2048 (was 1024: tail-bound)
#define ASTR 72            // Bs LDS row stride (bf16): b128 reads 2-way = free

// atomic buckets
#define NB 8
#define BSTR 512                 // floats per bucket
#define SCOFF (NB * BSTR)        // scale at ws[SCOFF..+63], shift at ws[SCOFF+64..+127]

typedef __attribute__((ext_vector_type(8))) short bf16x8;
typedef __attribute__((ext_vector_type(4))) float f32x4;

// ---------------- helpers ----------------

__device__ __forceinline__ float wave_reduce_add(float v) {
#pragma unroll
  for (int m = 32; m > 0; m >>= 1) v += __shfl_xor(v, m, 64);
  return v;
}

__device__ __forceinline__ unsigned short f2bf16(float x) {
  union { float f; unsigned u; } v; v.f = x;
  unsigned r = v.u + 0x7FFFu + ((v.u >> 16) & 1u);   // RTNE
  return (unsigned short)(r >> 16);
}

__device__ __forceinline__ bf16x8 cvt8(float4 lo, float4 hi) {
  bf16x8 r;
  r[0] = (short)f2bf16(lo.x); r[1] = (short)f2bf16(lo.y);
  r[2] = (short)f2bf16(lo.z); r[3] = (short)f2bf16(lo.w);
  r[4] = (short)f2bf16(hi.x); r[5] = (short)f2bf16(hi.y);
  r[6] = (short)f2bf16(hi.z); r[7] = (short)f2bf16(hi.w);
  return r;
}

// bucket layout (floats): [0]=sum w*nll [1]=sum w [2]=sum l1*m [3]=sum cos*m [4]=sum m
// [8..71]=sum_h  [72..135]=sum_h2 ; global: ws[SCOFF..]=BN scale, ws[SCOFF+64..]=BN shift

// ---------------- pass 1: pipelined MFMA dual-GEMM -> BN stats + CE ----------------
// h GEMM in [point,channel] layout (BN stats per-lane, reduced once at block end).
// Logit GEMM OPERAND-SWAPPED: D[class, point] so each point's 20 logits sit on the
// 4-lane quad axis -> CE = local 8-reg reduce + 2 shfl(16,32) chains (was ~50 dependent
// ds-ops/tile in the row-layout CE -- R7's latency bottleneck).
// __launch_bounds__(256,3): 170-reg budget ((256,4)'s 128 cap spilled af -> R5 240 MB writes).

__global__ __launch_bounds__(TPB, 3)
void pass1_kernel(const float* __restrict__ feat,
                  const int* __restrict__ segment,
                  const float* __restrict__ W1,
                  const float* __restrict__ Wseg,
                  const float* __restrict__ bseg,
                  const float* __restrict__ cw,
                  float* __restrict__ ws, int n) {
  __shared__ __align__(16) unsigned short Bs[96 * ASTR];  // W1^T rows 0..63, Wseg^T 64..95
  __shared__ float cred[512];                             // [2][4 waves][64 ch]
  __shared__ float wpart[8];

  const int t = threadIdx.x;
  const int wv = t >> 6;          // 0..3
  const int L = t & 63;
  const int colL = L & 15;
  const int quad = L >> 4;
  const long long blockbase = (long long)blockIdx.x * (ROWS_PER_TILE * NT);
  const int rbase = wv * 32;

  float* bucket = ws + (blockIdx.x & (NB - 1)) * BSTR;

  // persistent per-lane accumulators (across tiles)
  float s1[4] = {0, 0, 0, 0}, s2[4] = {0, 0, 0, 0};
  float wnll = 0.f, wsum = 0.f;

  // per-lane bseg for swapped-logit classes: tile0 row = quad*4+r, tile1 row 16+r (quad 0)
  float bsq0[4], bsq1[4];
#pragma unroll
  for (int r = 0; r < 4; ++r) {
    bsq0[r] = bseg[quad * 4 + r];
    bsq1[r] = (quad == 0) ? bseg[16 + r] : 0.f;
  }

  float4 af[8];   // prefetched feat fragments [rt*4 + kh*2 + half] -- must stay in VGPRs
  auto issue_tile = [&](int it) {
    const long long trow = blockbase + (long long)it * ROWS_PER_TILE + rbase;
    const float* frow = feat + (trow + colL) * C + quad * 8;
#pragma unroll
    for (int rt = 0; rt < 2; ++rt)
#pragma unroll
      for (int kh = 0; kh < 2; ++kh) {
        const float* p = frow + rt * (16 * C) + kh * 32;
        af[rt * 4 + kh * 2 + 0] = *(const float4*)p;
        af[rt * 4 + kh * 2 + 1] = *(const float4*)(p + 4);
      }
  };

  issue_tile(0);

  // stage W1^T (rows = out channel j, cols = k); covers tile-0 load latency
#pragma unroll
  for (int i = 0; i < 16; ++i) {
    int e = t + i * 256;                       // e = k*64 + j
    Bs[(e & 63) * ASTR + (e >> 6)] = f2bf16(W1[e]);
  }
  // stage Wseg^T padded to 32 output cols (pad rows zero)
#pragma unroll
  for (int i = 0; i < 8; ++i) {
    int e = t + i * 256;                       // over 64x32
    int k = e >> 5, j = e & 31;
    float v = (j < K) ? Wseg[k * K + j] : 0.0f;
    Bs[(64 + j) * ASTR + k] = f2bf16(v);
  }
  __syncthreads();   // Bs ready; never written again

  for (int it = 0; it < NT; ++it) {
    const long long trow = blockbase + (long long)it * ROWS_PER_TILE + rbase;
    // segment for this wave's two 16-point groups (point = colL; same across quads)
    int tg0 = segment[trow + colL];
    int tg1 = segment[trow + 16 + colL];

    // consume prefetched feat (vmcnt wait folds here), then issue next tile
    bf16x8 a[2][2];
#pragma unroll
    for (int rt = 0; rt < 2; ++rt)
#pragma unroll
      for (int kh = 0; kh < 2; ++kh)
        a[rt][kh] = cvt8(af[rt * 4 + kh * 2], af[rt * 4 + kh * 2 + 1]);
    if (it + 1 < NT) issue_tile(it + 1);

    // ---- h columns (ct 0..3), D[point, channel]: 16 MFMAs ----
    f32x4 ah[2][4];
#pragma unroll
    for (int rt = 0; rt < 2; ++rt)
#pragma unroll
      for (int ct = 0; ct < 4; ++ct) ah[rt][ct] = (f32x4){0.f, 0.f, 0.f, 0.f};
#pragma unroll
    for (int kh = 0; kh < 2; ++kh) {
      const int k0 = kh * 32 + quad * 8;
#pragma unroll
      for (int ct = 0; ct < 4; ++ct) {
        bf16x8 b = *(const bf16x8*)(Bs + (ct * 16 + colL) * ASTR + k0);
        ah[0][ct] = __builtin_amdgcn_mfma_f32_16x16x32_bf16(a[0][kh], b, ah[0][ct], 0, 0, 0);
        ah[1][ct] = __builtin_amdgcn_mfma_f32_16x16x32_bf16(a[1][kh], b, ah[1][ct], 0, 0, 0);
      }
    }

    // ---- BN stats (registers only) ----
#pragma unroll
    for (int rt = 0; rt < 2; ++rt)
#pragma unroll
      for (int ct = 0; ct < 4; ++ct) {
        float v0 = ah[rt][ct][0], v1 = ah[rt][ct][1];
        float v2 = ah[rt][ct][2], v3 = ah[rt][ct][3];
        s1[ct] += v0 + v1 + v2 + v3;
        s2[ct] = __builtin_fmaf(v0, v0, s2[ct]);
        s2[ct] = __builtin_fmaf(v1, v1, s2[ct]);
        s2[ct] = __builtin_fmaf(v2, v2, s2[ct]);
        s2[ct] = __builtin_fmaf(v3, v3, s2[ct]);
      }

    // ---- logits SWAPPED: D[class, point] = Wseg^T x feat^T : 8 MFMAs ----
    f32x4 alg[2][2];
#pragma unroll
    for (int rt = 0; rt < 2; ++rt)
#pragma unroll
      for (int cc = 0; cc < 2; ++cc) alg[rt][cc] = (f32x4){0.f, 0.f, 0.f, 0.f};
#pragma unroll
    for (int kh = 0; kh < 2; ++kh) {
      const int k0 = kh * 32 + quad * 8;
#pragma unroll
      for (int cc = 0; cc < 2; ++cc) {
        bf16x8 b = *(const bf16x8*)(Bs + ((4 + cc) * 16 + colL) * ASTR + k0);
        // swapped operand order: b (W^T rows = classes) is the A operand
        alg[0][cc] = __builtin_amdgcn_mfma_f32_16x16x32_bf16(b, a[0][kh], alg[0][cc], 0, 0, 0);
        alg[1][cc] = __builtin_amdgcn_mfma_f32_16x16x32_bf16(b, a[1][kh], alg[1][cc], 0, 0, 0);
      }
    }

    // ---- CE: per-lane 8 logits (classes quad*4+r and 16+r), quad-axis reduce ----
#pragma unroll
    for (int rt = 0; rt < 2; ++rt) {
      const int tg = rt ? tg1 : tg0;
      const bool valid = (tg != -1);
      const int tgt = valid ? tg : 0;
      float lg0[4], lg1[4];
#pragma unroll
      for (int r = 0; r < 4; ++r) {
        lg0[r] = alg[rt][0][r] + bsq0[r];
        lg1[r] = (quad == 0) ? alg[rt][1][r] + bsq1[r] : -3.0e38f;
      }
      float mx = fmaxf(fmaxf(fmaxf(lg0[0], lg0[1]), fmaxf(lg0[2], lg0[3])),
                       fmaxf(fmaxf(lg1[0], lg1[1]), fmaxf(lg1[2], lg1[3])));
      mx = fmaxf(mx, __shfl_xor(mx, 16, 64));
      mx = fmaxf(mx, __shfl_xor(mx, 32, 64));
      float e = 0.f, tp = 0.f;
#pragma unroll
      for (int r = 0; r < 4; ++r) {
        e += __expf(lg0[r] - mx) + __expf(lg1[r] - mx);
        tp += (quad * 4 + r == tgt) ? lg0[r] : 0.f;
        tp += (quad == 0 && 16 + r == tgt) ? lg1[r] : 0.f;
      }
      e += __shfl_xor(e, 16, 64);
      tp += __shfl_xor(tp, 16, 64);
      e += __shfl_xor(e, 32, 64);
      tp += __shfl_xor(tp, 32, 64);
      float nll = mx + __logf(e) - tp;
      if (quad == 0) {
        float w = valid ? cw[tgt] : 0.f;
        wnll += w * nll;
        wsum += w;
      }
    }
  }

  // ---- block-end reduction (amortized over NT tiles) ----
#pragma unroll
  for (int ct = 0; ct < 4; ++ct) {
    float a1 = s1[ct]; a1 += __shfl_xor(a1, 16, 64); a1 += __shfl_xor(a1, 32, 64);
    float a2 = s2[ct]; a2 += __shfl_xor(a2, 16, 64); a2 += __shfl_xor(a2, 32, 64);
    if (L < 16) { cred[wv * 64 + ct * 16 + colL] = a1; cred[256 + wv * 64 + ct * 16 + colL] = a2; }
  }
  {
    float rwn = wave_reduce_add(wnll);
    float rw = wave_reduce_add(wsum);
    if (L == 0) { wpart[wv * 2] = rwn; wpart[wv * 2 + 1] = rw; }
  }
  __syncthreads();
  if (t == 0) {
    atomicAdd(&bucket[0], wpart[0] + wpart[2] + wpart[4] + wpart[6]);
    atomicAdd(&bucket[1], wpart[1] + wpart[3] + wpart[5] + wpart[7]);
  }
  if (t < C) {
    float u1 = cred[t] + cred[64 + t] + cred[128 + t] + cred[192 + t];
    float u2 = cred[256 + t] + cred[320 + t] + cred[384 + t] + cred[448 + t];
    atomicAdd(&bucket[8 + t], u1);
    atomicAdd(&bucket[72 + t], u2);
  }
}

// ---------------- prep: fold BN stats into scale/shift once ----------------

__global__ void prep_kernel(const float* __restrict__ gamma,
                            const float* __restrict__ beta,
                            float* __restrict__ ws, int n) {
  int j = threadIdx.x;
  float s1 = 0.f, s2 = 0.f;
#pragma unroll
  for (int b = 0; b < NB; ++b) { s1 += ws[b * BSTR + 8 + j]; s2 += ws[b * BSTR + 72 + j]; }
  float inv_n = 1.0f / (float)n;
  float mean = s1 * inv_n;
  float var = fmaxf(s2 * inv_n - mean * mean, 0.0f);
  float sc = gamma[j] * rsqrtf(var + 1e-3f);
  ws[SCOFF + j] = sc;
  ws[SCOFF + 64 + j] = beta[j] - mean * sc;
}

// ---------------- pass 2: MFMA recompute of h (fp32 frags) + BN+ReLU+GEMV + losses -----
// Re-reads feat instead of an h round-trip: identical ideal traffic, pure-read streaming.

__global__ __launch_bounds__(TPB, 3)
void pass2_mfma(const float* __restrict__ feat,
                const float* __restrict__ coord,
                const int* __restrict__ instance,
                const float* __restrict__ centroid,
                const float* __restrict__ W1,
                const float* __restrict__ W2,
                const float* __restrict__ b2,
                float* __restrict__ ws, int n) {
  __shared__ __align__(16) unsigned short Bs[64 * ASTR];  // W1^T only
  __shared__ float part[4][3];

  const int t = threadIdx.x;
  const int wv = t >> 6, L = t & 63;
  const int colL = L & 15, quad = L >> 4;
  const long long blockbase = (long long)blockIdx.x * (ROWS_PER_TILE * NT);
  const int rbase = wv * 32;
  float* bucket = ws + (blockIdx.x & (NB - 1)) * BSTR;

  // per-lane BN scale/shift + W2 rows for channels ct*16+colL
  const float* ssc = ws + SCOFF;
  const float* ssh = ws + SCOFF + 64;
  float scv[4], shv[4], w20[4], w21[4], w22[4];
#pragma unroll
  for (int ct = 0; ct < 4; ++ct) {
    int j = ct * 16 + colL;
    scv[ct] = ssc[j];
    shv[ct] = ssh[j];
    w20[ct] = W2[j * 3 + 0];
    w21[ct] = W2[j * 3 + 1];
    w22[ct] = W2[j * 3 + 2];
  }
  const float bb0 = b2[0], bb1 = b2[1], bb2 = b2[2];

  float4 af[8];
  auto issue_tile = [&](int it) {
    const long long trow = blockbase + (long long)it * ROWS_PER_TILE + rbase;
    const float* frow = feat + (trow + colL) * C + quad * 8;
#pragma unroll
    for (int rt = 0; rt < 2; ++rt)
#pragma unroll
      for (int kh = 0; kh < 2; ++kh) {
        const float* p = frow + rt * (16 * C) + kh * 32;
        af[rt * 4 + kh * 2 + 0] = *(const float4*)p;
        af[rt * 4 + kh * 2 + 1] = *(const float4*)(p + 4);
      }
  };
  float pc[2][3], pg[2][3]; int pin[2];
  auto issue_pts = [&](int it) {
    if (colL < 4) {
      const long long rowb = blockbase + (long long)it * ROWS_PER_TILE +
                             rbase + quad * 4 + colL;
#pragma unroll
      for (int rt = 0; rt < 2; ++rt) {
        long long p = rowb + rt * 16;
        pc[rt][0] = coord[p * 3 + 0]; pc[rt][1] = coord[p * 3 + 1]; pc[rt][2] = coord[p * 3 + 2];
        pg[rt][0] = centroid[p * 3 + 0]; pg[rt][1] = centroid[p * 3 + 1]; pg[rt][2] = centroid[p * 3 + 2];
        pin[rt] = instance[p];
      }
    }
  };

  issue_tile(0);

  // stage W1^T; covers tile-0 load latency
#pragma unroll
  for (int i = 0; i < 16; ++i) {
    int e = t + i * 256;                       // e = k*64 + j
    Bs[(e & 63) * ASTR + (e >> 6)] = f2bf16(W1[e]);
  }
  __syncthreads();

  issue_pts(0);

  float l1a = 0.f, cosa = 0.f, ma = 0.f;

  for (int it = 0; it < NT; ++it) {
    bf16x8 a[2][2];
#pragma unroll
    for (int rt = 0; rt < 2; ++rt)
#pragma unroll
      for (int kh = 0; kh < 2; ++kh)
        a[rt][kh] = cvt8(af[rt * 4 + kh * 2], af[rt * 4 + kh * 2 + 1]);
    if (it + 1 < NT) issue_tile(it + 1);

    // h columns: 16 MFMAs (fp32 fragments, no bf16 rounding of h)
    f32x4 ah[2][4];
#pragma unroll
    for (int rt = 0; rt < 2; ++rt)
#pragma unroll
      for (int ct = 0; ct < 4; ++ct) ah[rt][ct] = (f32x4){0.f, 0.f, 0.f, 0.f};
#pragma unroll
    for (int kh = 0; kh < 2; ++kh) {
      const int k0 = kh * 32 + quad * 8;
#pragma unroll
      for (int ct = 0; ct < 4; ++ct) {
        bf16x8 b = *(const bf16x8*)(Bs + (ct * 16 + colL) * ASTR + k0);
        ah[0][ct] = __builtin_amdgcn_mfma_f32_16x16x32_bf16(a[0][kh], b, ah[0][ct], 0, 0, 0);
        ah[1][ct] = __builtin_amdgcn_mfma_f32_16x16x32_bf16(a[1][kh], b, ah[1][ct], 0, 0, 0);
      }
    }

    // BN+ReLU+W2 partials in-lane, butterfly over the 16-lane colL group
#pragma unroll
    for (int rt = 0; rt < 2; ++rt) {
      float d[12];
#pragma unroll
      for (int e = 0; e < 12; ++e) d[e] = 0.f;
#pragma unroll
      for (int ct = 0; ct < 4; ++ct) {
#pragma unroll
        for (int r = 0; r < 4; ++r) {
          float v = ah[rt][ct][r];
          float y = fmaxf(__builtin_fmaf(v, scv[ct], shv[ct]), 0.0f);
          d[r * 3 + 0] = __builtin_fmaf(y, w20[ct], d[r * 3 + 0]);
          d[r * 3 + 1] = __builtin_fmaf(y, w21[ct], d[r * 3 + 1]);
          d[r * 3 + 2] = __builtin_fmaf(y, w22[ct], d[r * 3 + 2]);
        }
      }
#pragma unroll
      for (int m = 1; m <= 8; m <<= 1)
#pragma unroll
        for (int e = 0; e < 12; ++e) d[e] += __shfl_xor(d[e], m, 64);
      if (colL < 4) {
        const int r = colL;
        float bp0 = d[r * 3 + 0] + bb0;
        float bp1 = d[r * 3 + 1] + bb1;
        float bp2 = d[r * 3 + 2] + bb2;
        float gx = pg[rt][0] - pc[rt][0];
        float gy = pg[rt][1] - pc[rt][1];
        float gz = pg[rt][2] - pc[rt][2];
        float m = (pin[rt] != -1) ? 1.0f : 0.0f;
        float l1 = fabsf(bp0 - gx) + fabsf(bp1 - gy) + fabsf(bp2 - gz);
        float npn = sqrtf(bp0 * bp0 + bp1 * bp1 + bp2 * bp2) + 1e-8f;
        float ngn = sqrtf(gx * gx + gy * gy + gz * gz) + 1e-8f;
        float cs = -(bp0 * gx + bp1 * gy + bp2 * gz) / (npn * ngn);
        l1a += l1 * m;
        cosa += cs * m;
        ma += m;
      }
    }
    if (it + 1 < NT) issue_pts(it + 1);
  }

  float r0 = wave_reduce_add(l1a);
  float r1 = wave_reduce_add(cosa);
  float r2 = wave_reduce_add(ma);
  if (L == 0) { part[wv][0] = r0; part[wv][1] = r1; part[wv][2] = r2; }
  __syncthreads();
  if (t == 0) {
    float a0 = 0, a1 = 0, a2 = 0;
#pragma unroll
    for (int k = 0; k < 4; ++k) { a0 += part[k][0]; a1 += part[k][1]; a2 += part[k][2]; }
    atomicAdd(&bucket[2], a0);
    atomicAdd(&bucket[3], a1);
    atomicAdd(&bucket[4], a2);
  }
}

// ---------------- finalize ----------------

__global__ void finalize_kernel(const float* __restrict__ ws, float* __restrict__ out) {
  if (threadIdx.x == 0 && blockIdx.x == 0) {
    float a0 = 0, a1 = 0, a2 = 0, a3 = 0, a4 = 0;
#pragma unroll
    for (int b = 0; b < NB; ++b) {
      const float* bk = ws + b * BSTR;
      a0 += bk[0]; a1 += bk[1]; a2 += bk[2]; a3 += bk[3]; a4 += bk[4];
    }
    float seg = a0 / a1;
    float den = a4 + 1e-8f;
    float l1 = a2 / den;
    float cs = a3 / den;
    out[0] = seg + l1 + cs;
    out[1] = seg;
    out[2] = l1;
    out[3] = cs;
  }
}

// ---------------- launch ----------------

extern "C" void kernel_launch(void* const* d_in, const int* in_sizes, int n_in,
                              void* d_out, int out_size, void* d_ws, size_t ws_size,
                              hipStream_t stream) {
  const float* feat = (const float*)d_in[0];
  const float* coord = (const float*)d_in[1];
  const int* segment = (const int*)d_in[2];
  const int* instance = (const int*)d_in[3];
  const float* centroid = (const float*)d_in[4];
  const float* W1 = (const float*)d_in[5];
  // d_in[6] = b1 : unused (BN train-mode output is invariant to channel shift)
  const float* gamma = (const float*)d_in[7];
  const float* beta = (const float*)d_in[8];
  const float* W2 = (const float*)d_in[9];
  const float* b2 = (const float*)d_in[10];
  const float* Wseg = (const float*)d_in[11];
  const float* bseg = (const float*)d_in[12];
  const float* cw = (const float*)d_in[13];

  const int n = in_sizes[0] / C;  // 1048576

  float* ws = (float*)d_ws;
  size_t zmax = (size_t)(NB * BSTR * 4);
  size_t zbytes = ws_size < zmax ? ws_size : zmax;
  hipMemsetAsync(d_ws, 0, zbytes, stream);

  const int nblk = n / (ROWS_PER_TILE * NT);   // 2048
  pass1_kernel<<<nblk, TPB, 0, stream>>>(feat, segment, W1, Wseg, bseg, cw, ws, n);
  prep_kernel<<<1, 64, 0, stream>>>(gamma, beta, ws, n);
  pass2_mfma<<<nblk, TPB, 0, stream>>>(feat, coord, instance, centroid,
                                       W1, W2, b2, ws, n);
  finalize_kernel<<<1, 1, 0, stream>>>(ws, (float*)d_out);
}